// Round 7
// baseline (3471.706 us; speedup 1.0000x reference)
//
#include <hip/hip_runtime.h>
#include <stdint.h>

// Problem constants
#define VOCAB  50000
#define EMBD   256
#define HIDD   512
#define G4     2048   // 4*HID
#define NBAT   256
#define TSEQ   512

// ---- workspace layout (bytes) ----
#define O_P2    0ull            // P2[v][j*4+g] bf16 : VOCAB*G4*2 = 204,800,000
#define O_EMBT  204800000ull    // emb bf16 [V][E] (dead after k_proj; hseq lives here)
#define O_WIH   230400000ull    // W_ih bf16 [G4][E]
#define O_WHH   231448576ull    // W_hh bf16 [G4][H]
#define O_TOKT  233545728ull    // tokT int [2][T][N]
#define WS_NEED 235643136ull
// rotating h exchange: [2 lstm][8 slots][N][H] bf16 = 16 x 262144 B = 4 MiB
#define O_HSEQ  O_EMBT
#define HSLOT   262144ull
#define SENT    0xFFFFFFFFFFFFFFFFull   // 4x bf16 -NaN: unreachable from finite h

typedef __bf16 bf16x8 __attribute__((ext_vector_type(8)));
typedef float  f32x4  __attribute__((ext_vector_type(4)));
typedef float  f32x16 __attribute__((ext_vector_type(16)));

__device__ __forceinline__ unsigned short f2bf(float x) {
  unsigned u = __float_as_uint(x);
  u = (u + 0x7fffu + ((u >> 16) & 1u)) >> 16;   // RNE
  return (unsigned short)u;
}
__device__ __forceinline__ float b2f(unsigned short b) {
  return __uint_as_float(((unsigned)b) << 16);
}
__device__ __forceinline__ float sigf(float x) {
  float e = __builtin_amdgcn_exp2f(-1.4426950408889634f * x);
  return __builtin_amdgcn_rcpf(1.0f + e);
}
__device__ __forceinline__ float tanhf_(float x) {
  float e = __builtin_amdgcn_exp2f(-2.8853900817779268f * x);
  return 2.0f * __builtin_amdgcn_rcpf(1.0f + e) - 1.0f;
}

// ------------------------------------------------------------------
// K1: prep — bf16 converts, token transpose
// ------------------------------------------------------------------
__global__ void k_prep(const float* __restrict__ emb, const float* __restrict__ wih,
                       const float* __restrict__ whh, const int* __restrict__ tok1,
                       const int* __restrict__ tok2, unsigned short* __restrict__ embT,
                       unsigned short* __restrict__ wihb, unsigned short* __restrict__ whhb,
                       int* __restrict__ tokT)
{
  const int stride = gridDim.x * blockDim.x;
  const int id0 = blockIdx.x * blockDim.x + threadIdx.x;
  for (int i = id0; i < VOCAB * EMBD; i += stride) embT[i] = f2bf(emb[i]);
  for (int i = id0; i < G4 * EMBD; i += stride)    wihb[i] = f2bf(wih[i]);
  for (int i = id0; i < G4 * HIDD; i += stride)    whhb[i] = f2bf(whh[i]);
  for (int i = id0; i < 2 * TSEQ * NBAT; i += stride) {
    int l = i >> 17, t = (i >> 8) & 511, n = i & 255;
    tokT[i] = (l ? tok2 : tok1)[n * TSEQ + t];
  }
}

// ------------------------------------------------------------------
// K1b: init h exchange slots (after k_proj — region overlaps dead embT).
// slot 0 (per lstm) = zeros (h(-1)); slots 1..7 = sentinel.
// ------------------------------------------------------------------
__global__ void k_hinit(unsigned long long* __restrict__ hseq)
{
  const int i = blockIdx.x * blockDim.x + threadIdx.x;   // 524288 total
  const int slot = i >> 15;                              // 32768 ull per slot
  hseq[i] = ((slot & 7) == 0) ? 0ull : SENT;
}

// ------------------------------------------------------------------
// K2: vocab projection  P2[v][j*4+g] = emb[v]·W_ih[g*512+j] + b_ih + b_hh
// (unchanged — round-1 correctness-verified)
// ------------------------------------------------------------------
__global__ __launch_bounds__(256) void
k_proj(const unsigned short* __restrict__ embT, const unsigned short* __restrict__ wihb,
       const float* __restrict__ bih, const float* __restrict__ bhh,
       unsigned short* __restrict__ P2)
{
  const int l  = threadIdx.x & 63;
  const int w  = threadIdx.x >> 6;
  const int n0 = blockIdx.x * 128 + (w & 1) * 64;
  const int m0 = blockIdx.y * 128 + (w >> 1) * 64;
  const int lq = l >> 4, lc = l & 15;

  f32x4 acc[4][4];
  #pragma unroll
  for (int a = 0; a < 4; ++a)
    #pragma unroll
    for (int b = 0; b < 4; ++b) acc[a][b] = (f32x4){0.f, 0.f, 0.f, 0.f};

  const uint8_t* eb = (const uint8_t*)embT;
  const uint8_t* wb = (const uint8_t*)wihb;
  #pragma unroll
  for (int ks = 0; ks < 8; ++ks) {
    const int koff = ks * 64 + lq * 16;
    bf16x8 a[4], b[4];
    #pragma unroll
    for (int mt = 0; mt < 4; ++mt) {
      int row = m0 + mt * 16 + lc; if (row >= VOCAB) row = VOCAB - 1;
      a[mt] = *(const bf16x8*)(eb + (size_t)row * 512 + koff);
    }
    #pragma unroll
    for (int nt = 0; nt < 4; ++nt) {
      int g = n0 + nt * 16 + lc;
      b[nt] = *(const bf16x8*)(wb + (size_t)g * 512 + koff);
    }
    #pragma unroll
    for (int mt = 0; mt < 4; ++mt)
      #pragma unroll
      for (int nt = 0; nt < 4; ++nt)
        acc[mt][nt] = __builtin_amdgcn_mfma_f32_16x16x32_bf16(a[mt], b[nt], acc[mt][nt], 0, 0, 0);
  }

  #pragma unroll
  for (int mt = 0; mt < 4; ++mt)
    #pragma unroll
    for (int r = 0; r < 4; ++r) {
      const int vrow = m0 + mt * 16 + lq * 4 + r;
      if (vrow < VOCAB) {
        #pragma unroll
        for (int nt = 0; nt < 4; ++nt) {
          const int gcol = n0 + nt * 16 + lc;
          float v = acc[mt][nt][r] + bih[gcol] + bhh[gcol];
          const int colp = ((gcol & 511) << 2) | (gcol >> 9);  // [j][g] permuted
          P2[(size_t)vrow * 2048 + colp] = f2bf(v);
        }
      }
    }
}

// ------------------------------------------------------------------
// K3: persistent LSTM scan (sentinel exchange + progressive chunks).
// 256 blocks x 256 threads (4 waves). block = (lstm, mg: 32 rows,
// jb: 32 cols). wave = gate. W_hh slice 128KB + h tile 32KB = 160KB LDS.
// Waves 0,2 own h chunk0 (hidden 0..255); waves 1,3 chunk1 — late waves
// poll AFTER GEMM-chunk0 (their loads in flight since step top).
// Gate buffer scatter-mapped into chunk0 LDS sub-region (dead post-B2).
// xq(t+1) prefetched during step t (issued after poll exit).
// ------------------------------------------------------------------
#define HL 131072
// scatter map for f32 gate buffer into per-row bytes 0..511 of h region
#define GBADDR(q) (smem + HL + ((size_t)((q) >> 7) << 10) + (((q) & 127) << 2))

__global__ __launch_bounds__(256, 1) void
k_lstm(const uint8_t* __restrict__ P2, const int* __restrict__ tokT,
       const uint8_t* __restrict__ whh, uint8_t* __restrict__ hseq)
{
  __shared__ __align__(16) uint8_t smem[163840];
  const int tid  = threadIdx.x;
  const int l    = tid & 63;
  const int w    = tid >> 6;        // wave = gate index
  const int bid  = blockIdx.x;
  const int jb   = bid & 15;
  const int mg   = (bid >> 4) & 7;
  const int lstm = bid >> 7;
  const int m0   = mg * 32;
  const int j0   = jb * 32;
  const bool early = ((w & 1) == 0);   // waves 0,2 = chunk0 stagers

  // ---- stage W_hh gate-slice into LDS once, xor-swizzled ----
  for (int i = 0; i < 32; ++i) {
    const int G = i * 256 + tid;            // chunk id 0..8191
    const int R = G >> 6, c = G & 63;
    const uint8_t* src = whh + (size_t)((R >> 5) * 512 + j0 + (R & 31)) * 1024 + (size_t)c * 16;
    const uint4 v = *(const uint4*)src;
    *(uint4*)(smem + (size_t)R * 1024 + ((c ^ (R & 7)) * 16)) = v;
  }

  const int em   = tid >> 3;        // epilogue batch row 0..31
  const int ecol = tid & 7;         // epilogue col group (4 cols)
  const int an   = l & 31;          // MFMA A-row / B-col (lane&31)
  const int ah   = l >> 5;          // k-half (lane>>5)
  const int Rrow = w * 32 + an;     // B LDS row

  float cst[4] = {0.f, 0.f, 0.f, 0.f};

  // ---- prologue: xq(0) direct; token for t=1 ----
  uint4 pf0, pf1;
  {
    const int tok0 = tokT[(lstm * TSEQ + 0) * NBAT + m0 + em];
    const uint8_t* xs = P2 + (size_t)tok0 * 4096 + (size_t)j0 * 8 + (size_t)ecol * 32;
    pf0 = *(const uint4*)(xs);
    pf1 = *(const uint4*)(xs + 16);
  }
  int tok_nn = tokT[(lstm * TSEQ + 1) * NBAT + m0 + em];

  for (int t = 0; t < TSEQ; ++t) {
    const uint4 xq0 = pf0, xq1 = pf1;   // this step's xg (prefetched)

    // ---- issue all 16 h(t) poll loads (both chunks, all waves) ----
    const uint8_t* hb = hseq + (size_t)(lstm * 8 + (t & 7)) * HSLOT
                      + (size_t)m0 * 1024 + (size_t)tid * 8;
    unsigned long long v[16];
    #pragma unroll
    for (int i = 0; i < 16; ++i)
      v[i] = __hip_atomic_load((const unsigned long long*)(hb + (size_t)i * 2048),
                               __ATOMIC_RELAXED, __HIP_MEMORY_SCOPE_AGENT);

    // ---- early waves: poll + stage chunk0 before B1 ----
    if (early) {
      unsigned valid = 0;
      int guard = 0;
      for (;;) {
        #pragma unroll
        for (int i = 0; i < 16; ++i)
          if (!(valid & (1u << i)) && v[i] != SENT) valid |= (1u << i);
        if (valid == 0xFFFFu) break;
        __builtin_amdgcn_s_sleep(1);
        #pragma unroll
        for (int i = 0; i < 16; ++i)
          if (!(valid & (1u << i)))
            v[i] = __hip_atomic_load((const unsigned long long*)(hb + (size_t)i * 2048),
                                     __ATOMIC_RELAXED, __HIP_MEMORY_SCOPE_AGENT);
        if (++guard > 1000000) break;   // fail visible, not hung
      }
      #pragma unroll
      for (int i = 0; i < 16; ++i) {
        const int m = i * 2 + (tid >> 7);
        const int c = (tid >> 1) & 63;
        const int half = tid & 1;
        *(unsigned long long*)(smem + HL + (size_t)m * 1024
                               + ((c ^ (m & 7)) * 16) + half * 8) = v[i];
      }
    }

    // ---- prefetch xq(t+1) + token(t+2): after polls, before barriers ----
    if (t + 1 < TSEQ) {
      const uint8_t* xs = P2 + (size_t)tok_nn * 4096 + (size_t)j0 * 8 + (size_t)ecol * 32;
      pf0 = *(const uint4*)(xs);
      pf1 = *(const uint4*)(xs + 16);
      if (t + 2 < TSEQ) tok_nn = tokT[(lstm * TSEQ + (t + 2)) * NBAT + m0 + em];
    }

    __syncthreads();   // B1: chunk0 staged

    // ---- GEMM chunk0: k-steps 0..15 (hidden 0..255) ----
    f32x16 acc0{}, acc1{};
    #pragma unroll
    for (int ks = 0; ks < 16; ++ks) {
      const int ch = ks * 2 + ah;
      const bf16x8 av = *(const bf16x8*)(smem + HL + (size_t)an * 1024 + ((ch ^ (an & 7)) * 16));
      const bf16x8 bv = *(const bf16x8*)(smem + (size_t)Rrow * 1024 + ((ch ^ (an & 7)) * 16));
      if (ks & 1) acc1 = __builtin_amdgcn_mfma_f32_32x32x16_bf16(av, bv, acc1, 0, 0, 0);
      else        acc0 = __builtin_amdgcn_mfma_f32_32x32x16_bf16(av, bv, acc0, 0, 0, 0);
    }

    // ---- late waves: poll + stage chunk1 (loads long in flight) ----
    if (!early) {
      unsigned valid = 0;
      int guard = 0;
      for (;;) {
        #pragma unroll
        for (int i = 0; i < 16; ++i)
          if (!(valid & (1u << i)) && v[i] != SENT) valid |= (1u << i);
        if (valid == 0xFFFFu) break;
        __builtin_amdgcn_s_sleep(1);
        #pragma unroll
        for (int i = 0; i < 16; ++i)
          if (!(valid & (1u << i)))
            v[i] = __hip_atomic_load((const unsigned long long*)(hb + (size_t)i * 2048),
                                     __ATOMIC_RELAXED, __HIP_MEMORY_SCOPE_AGENT);
        if (++guard > 1000000) break;   // fail visible, not hung
      }
      #pragma unroll
      for (int i = 0; i < 16; ++i) {
        const int m = i * 2 + (tid >> 7);
        const int c = (tid >> 1) & 63;
        const int half = tid & 1;
        *(unsigned long long*)(smem + HL + (size_t)m * 1024
                               + ((c ^ (m & 7)) * 16) + half * 8) = v[i];
      }
    }

    __syncthreads();   // B2: chunk1 staged; everyone's chunk0 reads done

    // ---- GEMM chunk1: k-steps 16..31 (hidden 256..511) ----
    #pragma unroll
    for (int ks = 16; ks < 32; ++ks) {
      const int ch = ks * 2 + ah;
      const bf16x8 av = *(const bf16x8*)(smem + HL + (size_t)an * 1024 + ((ch ^ (an & 7)) * 16));
      const bf16x8 bv = *(const bf16x8*)(smem + (size_t)Rrow * 1024 + ((ch ^ (an & 7)) * 16));
      if (ks & 1) acc1 = __builtin_amdgcn_mfma_f32_32x32x16_bf16(av, bv, acc1, 0, 0, 0);
      else        acc0 = __builtin_amdgcn_mfma_f32_32x32x16_bf16(av, bv, acc0, 0, 0, 0);
    }

    // ---- gate write into chunk0 scatter region (chunk0 dead post-B2) ----
    #pragma unroll
    for (int r = 0; r < 16; ++r) {
      const int row = (r & 3) + 8 * (r >> 2) + 4 * ah;   // 32x32 C/D mapping
      *(float*)GBADDR(w * 1024 + row * 32 + an) = acc0[r] + acc1[r];
    }
    __syncthreads();   // B3: gates visible

    // ---- epilogue: 4 cells/lane; h(t+1) -> slot (t+1)&7; re-sentinel (t+5)&7 ----
    {
      const int qb = em * 32 + ecol * 4;
      const f32x4 pi = *(const f32x4*)GBADDR(0 * 1024 + qb);
      const f32x4 pf = *(const f32x4*)GBADDR(1 * 1024 + qb);
      const f32x4 pg = *(const f32x4*)GBADDR(2 * 1024 + qb);
      const f32x4 po = *(const f32x4*)GBADDR(3 * 1024 + qb);
      unsigned short xsv[16];
      *(uint4*)(xsv) = xq0;
      *(uint4*)(xsv + 8) = xq1;
      unsigned short hv[4];
      #pragma unroll
      for (int k = 0; k < 4; ++k) {
        const float iv = sigf(pi[k] + b2f(xsv[k * 4 + 0]));
        const float fv = sigf(pf[k] + b2f(xsv[k * 4 + 1]));
        const float gv = tanhf_(pg[k] + b2f(xsv[k * 4 + 2]));
        const float ov = sigf(po[k] + b2f(xsv[k * 4 + 3]));
        const float cv = fv * cst[k] + iv * gv;
        cst[k] = cv;
        hv[k] = f2bf(ov * tanhf_(cv));
      }
      unsigned long long hp =
          (unsigned long long)hv[0] | ((unsigned long long)hv[1] << 16) |
          ((unsigned long long)hv[2] << 32) | ((unsigned long long)hv[3] << 48);
      const size_t tileoff = (size_t)(m0 + em) * 1024 + (size_t)(j0 + ecol * 4) * 2;
      uint8_t* hdst = hseq + (size_t)(lstm * 8 + ((t + 1) & 7)) * HSLOT + tileoff;
      __hip_atomic_store((unsigned long long*)hdst, hp,
                         __ATOMIC_RELAXED, __HIP_MEMORY_SCOPE_AGENT);
      uint8_t* rdst = hseq + (size_t)(lstm * 8 + ((t + 5) & 7)) * HSLOT + tileoff;
      __hip_atomic_store((unsigned long long*)rdst, SENT,
                         __ATOMIC_RELAXED, __HIP_MEMORY_SCOPE_AGENT);
    }
    __syncthreads();   // B4: gate reads done -> h region writable next step
  }
}

// ------------------------------------------------------------------
// K4: h1*h2 -> logits -> softmax. one wave per batch row.
// final h(512) lives in slot 512&7 = 0 of each lstm.
// ------------------------------------------------------------------
__global__ __launch_bounds__(64) void
k_fc(const uint8_t* __restrict__ hseq, const float* __restrict__ wfc,
     const float* __restrict__ bfc, float* __restrict__ out)
{
  const int n = blockIdx.x, l = threadIdx.x;
  const unsigned short* h1 = (const unsigned short*)(hseq + (size_t)n * 1024);
  const unsigned short* h2 = (const unsigned short*)(hseq + 8 * HSLOT + (size_t)n * 1024);
  float s0 = 0.f, s1 = 0.f;
  for (int j = l; j < HIDD; j += 64) {
    float hv = b2f(h1[j]) * b2f(h2[j]);
    s0 += hv * wfc[j];
    s1 += hv * wfc[HIDD + j];
  }
  #pragma unroll
  for (int off = 32; off > 0; off >>= 1) {
    s0 += __shfl_down(s0, off, 64);
    s1 += __shfl_down(s1, off, 64);
  }
  if (l == 0) {
    s0 += bfc[0]; s1 += bfc[1];
    float m  = fmaxf(s0, s1);
    float e0 = __builtin_amdgcn_exp2f((s0 - m) * 1.4426950408889634f);
    float e1 = __builtin_amdgcn_exp2f((s1 - m) * 1.4426950408889634f);
    float inv = 1.0f / (e0 + e1);
    out[n * 2 + 0] = e0 * inv;
    out[n * 2 + 1] = e1 * inv;
  }
}

// ------------------------------------------------------------------
extern "C" void kernel_launch(void* const* d_in, const int* in_sizes, int n_in,
                              void* d_out, int out_size, void* d_ws, size_t ws_size,
                              hipStream_t stream) {
  (void)in_sizes; (void)n_in; (void)out_size;
  if (ws_size < WS_NEED) return;   // fail visibly rather than scribble OOB

  const int*   tok1 = (const int*)d_in[0];
  const int*   tok2 = (const int*)d_in[1];
  const float* emb  = (const float*)d_in[2];
  const float* wih  = (const float*)d_in[3];
  const float* whh  = (const float*)d_in[4];
  const float* bih  = (const float*)d_in[5];
  const float* bhh  = (const float*)d_in[6];
  const float* wfc  = (const float*)d_in[7];
  const float* bfc  = (const float*)d_in[8];
  float* out = (float*)d_out;

  uint8_t* ws = (uint8_t*)d_ws;
  unsigned short* P2   = (unsigned short*)(ws + O_P2);
  unsigned short* embT = (unsigned short*)(ws + O_EMBT);
  unsigned short* wihb = (unsigned short*)(ws + O_WIH);
  unsigned short* whhb = (unsigned short*)(ws + O_WHH);
  int*            tokT = (int*)(ws + O_TOKT);
  uint8_t*        hseq = ws + O_HSEQ;

  k_prep<<<1024, 256, 0, stream>>>(emb, wih, whh, tok1, tok2, embT, wihb, whhb, tokT);
  k_proj<<<dim3(16, 391), 256, 0, stream>>>(embT, wihb, bih, bhh, P2);
  k_hinit<<<2048, 256, 0, stream>>>((unsigned long long*)hseq);  // embT dead after k_proj

  {
    const uint8_t* p2p = (const uint8_t*)P2;
    const int*     tkp = tokT;
    const uint8_t* whp = (const uint8_t*)whhb;
    uint8_t*       hsp = hseq;
    void* args[4] = {(void*)&p2p, (void*)&tkp, (void*)&whp, (void*)&hsp};
    hipError_t e = hipLaunchCooperativeKernel((void*)k_lstm, dim3(256), dim3(256),
                                              args, 0, stream);
    if (e != hipSuccess) {
      (void)hipGetLastError();  // clear; fall back (256 blocks @ 1/CU are co-resident)
      k_lstm<<<256, 256, 0, stream>>>(p2p, tkp, whp, hsp);
    }
  }

  k_fc<<<256, 64, 0, stream>>>(hseq, wfc, bfc, out);
}

// Round 8
// 2445.706 us; speedup vs baseline: 1.4195x; 1.4195x over previous
//
#include <hip/hip_runtime.h>
#include <stdint.h>

// Problem constants
#define VOCAB  50000
#define EMBD   256
#define HIDD   512
#define G4     2048   // 4*HID
#define NBAT   256
#define TSEQ   512

// ---- workspace layout (bytes) ----
#define O_P2    0ull            // P2[v][j*4+g] bf16 : VOCAB*G4*2 = 204,800,000
#define O_EMBT  204800000ull    // emb bf16 [V][E] (dead after k_proj; hseq lives here)
#define O_WIH   230400000ull    // W_ih bf16 [G4][E]
#define O_WHH   231448576ull    // W_hh bf16 [G4][H]
#define O_TOKT  233545728ull    // tokT int [2][T][N]
#define WS_NEED 235643136ull
// rotating h exchange: [2 lstm][8 slots][N][H] bf16 = 16 x 262144 B = 4 MiB
#define O_HSEQ  O_EMBT
#define HSLOT   262144ull
#define SENT    0xFFFFFFFFFFFFFFFFull   // 4x bf16 -NaN: unreachable from finite h

typedef __bf16 bf16x8 __attribute__((ext_vector_type(8)));
typedef float  f32x4  __attribute__((ext_vector_type(4)));
typedef float  f32x16 __attribute__((ext_vector_type(16)));

__device__ __forceinline__ unsigned short f2bf(float x) {
  unsigned u = __float_as_uint(x);
  u = (u + 0x7fffu + ((u >> 16) & 1u)) >> 16;   // RNE
  return (unsigned short)u;
}
__device__ __forceinline__ float b2f(unsigned short b) {
  return __uint_as_float(((unsigned)b) << 16);
}
__device__ __forceinline__ float sigf(float x) {
  float e = __builtin_amdgcn_exp2f(-1.4426950408889634f * x);
  return __builtin_amdgcn_rcpf(1.0f + e);
}
__device__ __forceinline__ float tanhf_(float x) {
  float e = __builtin_amdgcn_exp2f(-2.8853900817779268f * x);
  return 2.0f * __builtin_amdgcn_rcpf(1.0f + e) - 1.0f;
}

// ------------------------------------------------------------------
// K1: prep — bf16 converts, token transpose
// ------------------------------------------------------------------
__global__ void k_prep(const float* __restrict__ emb, const float* __restrict__ wih,
                       const float* __restrict__ whh, const int* __restrict__ tok1,
                       const int* __restrict__ tok2, unsigned short* __restrict__ embT,
                       unsigned short* __restrict__ wihb, unsigned short* __restrict__ whhb,
                       int* __restrict__ tokT)
{
  const int stride = gridDim.x * blockDim.x;
  const int id0 = blockIdx.x * blockDim.x + threadIdx.x;
  for (int i = id0; i < VOCAB * EMBD; i += stride) embT[i] = f2bf(emb[i]);
  for (int i = id0; i < G4 * EMBD; i += stride)    wihb[i] = f2bf(wih[i]);
  for (int i = id0; i < G4 * HIDD; i += stride)    whhb[i] = f2bf(whh[i]);
  for (int i = id0; i < 2 * TSEQ * NBAT; i += stride) {
    int l = i >> 17, t = (i >> 8) & 511, n = i & 255;
    tokT[i] = (l ? tok2 : tok1)[n * TSEQ + t];
  }
}

// ------------------------------------------------------------------
// K1b: init h exchange slots (after k_proj — region overlaps dead embT).
// slot 0 (per lstm) = zeros (h(-1)); slots 1..7 = sentinel.
// ------------------------------------------------------------------
__global__ void k_hinit(unsigned long long* __restrict__ hseq)
{
  const int i = blockIdx.x * blockDim.x + threadIdx.x;   // 524288 total
  const int slot = i >> 15;                              // 32768 ull per slot
  hseq[i] = ((slot & 7) == 0) ? 0ull : SENT;
}

// ------------------------------------------------------------------
// K2: vocab projection  P2[v][j*4+g] = emb[v]·W_ih[g*512+j] + b_ih + b_hh
// (unchanged — round-1 correctness-verified)
// ------------------------------------------------------------------
__global__ __launch_bounds__(256) void
k_proj(const unsigned short* __restrict__ embT, const unsigned short* __restrict__ wihb,
       const float* __restrict__ bih, const float* __restrict__ bhh,
       unsigned short* __restrict__ P2)
{
  const int l  = threadIdx.x & 63;
  const int w  = threadIdx.x >> 6;
  const int n0 = blockIdx.x * 128 + (w & 1) * 64;
  const int m0 = blockIdx.y * 128 + (w >> 1) * 64;
  const int lq = l >> 4, lc = l & 15;

  f32x4 acc[4][4];
  #pragma unroll
  for (int a = 0; a < 4; ++a)
    #pragma unroll
    for (int b = 0; b < 4; ++b) acc[a][b] = (f32x4){0.f, 0.f, 0.f, 0.f};

  const uint8_t* eb = (const uint8_t*)embT;
  const uint8_t* wb = (const uint8_t*)wihb;
  #pragma unroll
  for (int ks = 0; ks < 8; ++ks) {
    const int koff = ks * 64 + lq * 16;
    bf16x8 a[4], b[4];
    #pragma unroll
    for (int mt = 0; mt < 4; ++mt) {
      int row = m0 + mt * 16 + lc; if (row >= VOCAB) row = VOCAB - 1;
      a[mt] = *(const bf16x8*)(eb + (size_t)row * 512 + koff);
    }
    #pragma unroll
    for (int nt = 0; nt < 4; ++nt) {
      int g = n0 + nt * 16 + lc;
      b[nt] = *(const bf16x8*)(wb + (size_t)g * 512 + koff);
    }
    #pragma unroll
    for (int mt = 0; mt < 4; ++mt)
      #pragma unroll
      for (int nt = 0; nt < 4; ++nt)
        acc[mt][nt] = __builtin_amdgcn_mfma_f32_16x16x32_bf16(a[mt], b[nt], acc[mt][nt], 0, 0, 0);
  }

  #pragma unroll
  for (int mt = 0; mt < 4; ++mt)
    #pragma unroll
    for (int r = 0; r < 4; ++r) {
      const int vrow = m0 + mt * 16 + lq * 4 + r;
      if (vrow < VOCAB) {
        #pragma unroll
        for (int nt = 0; nt < 4; ++nt) {
          const int gcol = n0 + nt * 16 + lc;
          float v = acc[mt][nt][r] + bih[gcol] + bhh[gcol];
          const int colp = ((gcol & 511) << 2) | (gcol >> 9);  // [j][g] permuted
          P2[(size_t)vrow * 2048 + colp] = f2bf(v);
        }
      }
    }
}

// ------------------------------------------------------------------
// K3: persistent LSTM scan (round-6 sentinel exchange, LATE-DRAIN
// barrier schedule). 256 blocks x 256 threads (4 waves).
// block = (lstm, mg: 32 rows, jb: 32 cols). wave = gate.
// W_hh slice 128KB + h tile 32KB = 160KB LDS.
// KEY CHANGE vs round 6: the last barrier (B4) sits between the
// gate-collect (LDS->reg) and the nonlinearity+stores, so the h /
// re-sentinel stores are issued with NO following barrier — they age
// through the next step's poll window and drain for free at B1. The
// poll's own vmcnt(0) overlaps store-ack with peer-data load RT
// (max instead of sum of two MALL latencies).
// ------------------------------------------------------------------
#define HL 131072

__global__ __launch_bounds__(256, 1) void
k_lstm(const uint8_t* __restrict__ P2, const int* __restrict__ tokT,
       const uint8_t* __restrict__ whh, uint8_t* __restrict__ hseq)
{
  __shared__ __align__(16) uint8_t smem[163840];
  const int tid  = threadIdx.x;
  const int l    = tid & 63;
  const int w    = tid >> 6;        // wave = gate index
  const int bid  = blockIdx.x;
  const int jb   = bid & 15;
  const int mg   = (bid >> 4) & 7;
  const int lstm = bid >> 7;
  const int m0   = mg * 32;
  const int j0   = jb * 32;

  // ---- stage W_hh gate-slice into LDS once, xor-swizzled ----
  // LDS row R = g*32 + jl  <->  W_hh row g*512 + j0 + jl ; 16B chunk c at (c ^ (R&7))
  for (int i = 0; i < 32; ++i) {
    const int G = i * 256 + tid;            // chunk id 0..8191
    const int R = G >> 6, c = G & 63;
    const uint8_t* src = whh + (size_t)((R >> 5) * 512 + j0 + (R & 31)) * 1024 + (size_t)c * 16;
    const uint4 v = *(const uint4*)src;
    *(uint4*)(smem + (size_t)R * 1024 + ((c ^ (R & 7)) * 16)) = v;
  }

  const int em   = tid >> 3;        // epilogue batch row 0..31
  const int ecol = tid & 7;         // epilogue col group (4 cols)
  const int an   = l & 31;          // MFMA A-row / B-col (lane&31)
  const int ah   = l >> 5;          // k-half (lane>>5)
  const int Rrow = w * 32 + an;     // B LDS row

  float cst[4] = {0.f, 0.f, 0.f, 0.f};
  int tok_next = tokT[(lstm * TSEQ + 0) * NBAT + m0 + em];

  for (int t = 0; t < TSEQ; ++t) {
    const int tok_cur = tok_next;

    // ---- issue xg gather + next-token load first (overlaps the poll) ----
    const uint8_t* xsrc = P2 + (size_t)tok_cur * 4096 + (size_t)j0 * 8 + (size_t)ecol * 32;
    const uint4 xq0 = *(const uint4*)(xsrc);
    const uint4 xq1 = *(const uint4*)(xsrc + 16);
    if (t + 1 < TSEQ) tok_next = tokT[(lstm * TSEQ + (t + 1)) * NBAT + m0 + em];

    // ---- poll-stage h(t): sentinel-checked data words -> LDS ----
    // (prev step's h/sentinel stores are still in flight here; the poll's
    //  vmcnt waits overlap their ack with the peer-data load RT)
    {
      const uint8_t* hb = hseq + (size_t)(lstm * 8 + (t & 7)) * HSLOT
                        + (size_t)m0 * 1024 + (size_t)tid * 8;
      unsigned long long v[16];
      #pragma unroll
      for (int i = 0; i < 16; ++i)
        v[i] = __hip_atomic_load((const unsigned long long*)(hb + (size_t)i * 2048),
                                 __ATOMIC_RELAXED, __HIP_MEMORY_SCOPE_AGENT);
      unsigned valid = 0;
      int guard = 0;
      for (;;) {
        #pragma unroll
        for (int i = 0; i < 16; ++i)
          if (!(valid & (1u << i)) && v[i] != SENT) valid |= (1u << i);
        if (valid == 0xFFFFu) break;
        __builtin_amdgcn_s_sleep(1);
        #pragma unroll
        for (int i = 0; i < 16; ++i)
          if (!(valid & (1u << i)))
            v[i] = __hip_atomic_load((const unsigned long long*)(hb + (size_t)i * 2048),
                                     __ATOMIC_RELAXED, __HIP_MEMORY_SCOPE_AGENT);
        if (++guard > 1000000) break;   // fail visible, not hung
      }
      #pragma unroll
      for (int i = 0; i < 16; ++i) {
        const int m = i * 2 + (tid >> 7);
        const int c = (tid >> 1) & 63;
        const int half = tid & 1;
        *(unsigned long long*)(smem + HL + (size_t)m * 1024
                               + ((c ^ (m & 7)) * 16) + half * 8) = v[i];
      }
    }
    __syncthreads();   // B1: h LDS ready (prev stores aged through poll -> ~free drain)

    // ---- GEMM: gate_w[32x32] = h[32x512] . W_g[32x512]^T (32x32x16 MFMA) ----
    f32x16 acc0{}, acc1{};
    #pragma unroll 8
    for (int ks = 0; ks < 32; ++ks) {
      const int ch = ks * 2 + ah;
      const bf16x8 av = *(const bf16x8*)(smem + HL + (size_t)an * 1024 + ((ch ^ (an & 7)) * 16));
      const bf16x8 bv = *(const bf16x8*)(smem + (size_t)Rrow * 1024 + ((ch ^ (an & 7)) * 16));
      if (ks & 1) acc1 = __builtin_amdgcn_mfma_f32_32x32x16_bf16(av, bv, acc1, 0, 0, 0);
      else        acc0 = __builtin_amdgcn_mfma_f32_32x32x16_bf16(av, bv, acc0, 0, 0, 0);
    }
    __syncthreads();   // B2: A reads done; h region reusable as f32 gate buffer

    {
      float* gb = (float*)(smem + HL);   // gbuf[g][row 0..31][col 0..31] f32
      #pragma unroll
      for (int r = 0; r < 16; ++r) {
        const int row = (r & 3) + 8 * (r >> 2) + 4 * ah;   // 32x32 C/D mapping
        gb[w * 1024 + row * 32 + an] = acc0[r] + acc1[r];
      }
    }
    __syncthreads();   // B3: gate buffer visible

    // ---- gate-collect: LDS -> registers (reads only, no stores yet) ----
    const float* gb = (const float*)(smem + HL);
    const f32x4 pi = *(const f32x4*)(gb + 0 * 1024 + em * 32 + ecol * 4);
    const f32x4 pf = *(const f32x4*)(gb + 1 * 1024 + em * 32 + ecol * 4);
    const f32x4 pg = *(const f32x4*)(gb + 2 * 1024 + em * 32 + ecol * 4);
    const f32x4 po = *(const f32x4*)(gb + 3 * 1024 + em * 32 + ecol * 4);

    __syncthreads();   // B4: gate reads done -> LDS free for next step's staging.
                       // NO barrier follows the stores below.

    // ---- nonlinearity + h(t+1) -> slot (t+1)&7; re-sentinel (t+5)&7 ----
    {
      unsigned short xsv[16];
      *(uint4*)(xsv) = xq0;
      *(uint4*)(xsv + 8) = xq1;
      unsigned short hv[4];
      #pragma unroll
      for (int k = 0; k < 4; ++k) {
        const float iv = sigf(pi[k] + b2f(xsv[k * 4 + 0]));
        const float fv = sigf(pf[k] + b2f(xsv[k * 4 + 1]));
        const float gv = tanhf_(pg[k] + b2f(xsv[k * 4 + 2]));
        const float ov = sigf(po[k] + b2f(xsv[k * 4 + 3]));
        const float cv = fv * cst[k] + iv * gv;
        cst[k] = cv;
        hv[k] = f2bf(ov * tanhf_(cv));
      }
      unsigned long long hp =
          (unsigned long long)hv[0] | ((unsigned long long)hv[1] << 16) |
          ((unsigned long long)hv[2] << 32) | ((unsigned long long)hv[3] << 48);
      const size_t tileoff = (size_t)(m0 + em) * 1024 + (size_t)(j0 + ecol * 4) * 2;
      uint8_t* hdst = hseq + (size_t)(lstm * 8 + ((t + 1) & 7)) * HSLOT + tileoff;
      __hip_atomic_store((unsigned long long*)hdst, hp,
                         __ATOMIC_RELAXED, __HIP_MEMORY_SCOPE_AGENT);
      uint8_t* rdst = hseq + (size_t)(lstm * 8 + ((t + 5) & 7)) * HSLOT + tileoff;
      __hip_atomic_store((unsigned long long*)rdst, SENT,
                         __ATOMIC_RELAXED, __HIP_MEMORY_SCOPE_AGENT);
    }
    // loop top: poll window ages these stores before B1 drains them
  }
}

// ------------------------------------------------------------------
// K4: h1*h2 -> logits -> softmax. one wave per batch row.
// final h(512) lives in slot 512&7 = 0 of each lstm.
// ------------------------------------------------------------------
__global__ __launch_bounds__(64) void
k_fc(const uint8_t* __restrict__ hseq, const float* __restrict__ wfc,
     const float* __restrict__ bfc, float* __restrict__ out)
{
  const int n = blockIdx.x, l = threadIdx.x;
  const unsigned short* h1 = (const unsigned short*)(hseq + (size_t)n * 1024);
  const unsigned short* h2 = (const unsigned short*)(hseq + 8 * HSLOT + (size_t)n * 1024);
  float s0 = 0.f, s1 = 0.f;
  for (int j = l; j < HIDD; j += 64) {
    float hv = b2f(h1[j]) * b2f(h2[j]);
    s0 += hv * wfc[j];
    s1 += hv * wfc[HIDD + j];
  }
  #pragma unroll
  for (int off = 32; off > 0; off >>= 1) {
    s0 += __shfl_down(s0, off, 64);
    s1 += __shfl_down(s1, off, 64);
  }
  if (l == 0) {
    s0 += bfc[0]; s1 += bfc[1];
    float m  = fmaxf(s0, s1);
    float e0 = __builtin_amdgcn_exp2f((s0 - m) * 1.4426950408889634f);
    float e1 = __builtin_amdgcn_exp2f((s1 - m) * 1.4426950408889634f);
    float inv = 1.0f / (e0 + e1);
    out[n * 2 + 0] = e0 * inv;
    out[n * 2 + 1] = e1 * inv;
  }
}

// ------------------------------------------------------------------
extern "C" void kernel_launch(void* const* d_in, const int* in_sizes, int n_in,
                              void* d_out, int out_size, void* d_ws, size_t ws_size,
                              hipStream_t stream) {
  (void)in_sizes; (void)n_in; (void)out_size;
  if (ws_size < WS_NEED) return;   // fail visibly rather than scribble OOB

  const int*   tok1 = (const int*)d_in[0];
  const int*   tok2 = (const int*)d_in[1];
  const float* emb  = (const float*)d_in[2];
  const float* wih  = (const float*)d_in[3];
  const float* whh  = (const float*)d_in[4];
  const float* bih  = (const float*)d_in[5];
  const float* bhh  = (const float*)d_in[6];
  const float* wfc  = (const float*)d_in[7];
  const float* bfc  = (const float*)d_in[8];
  float* out = (float*)d_out;

  uint8_t* ws = (uint8_t*)d_ws;
  unsigned short* P2   = (unsigned short*)(ws + O_P2);
  unsigned short* embT = (unsigned short*)(ws + O_EMBT);
  unsigned short* wihb = (unsigned short*)(ws + O_WIH);
  unsigned short* whhb = (unsigned short*)(ws + O_WHH);
  int*            tokT = (int*)(ws + O_TOKT);
  uint8_t*        hseq = ws + O_HSEQ;

  k_prep<<<1024, 256, 0, stream>>>(emb, wih, whh, tok1, tok2, embT, wihb, whhb, tokT);
  k_proj<<<dim3(16, 391), 256, 0, stream>>>(embT, wihb, bih, bhh, P2);
  k_hinit<<<2048, 256, 0, stream>>>((unsigned long long*)hseq);  // embT dead after k_proj

  {
    const uint8_t* p2p = (const uint8_t*)P2;
    const int*     tkp = tokT;
    const uint8_t* whp = (const uint8_t*)whhb;
    uint8_t*       hsp = hseq;
    void* args[4] = {(void*)&p2p, (void*)&tkp, (void*)&whp, (void*)&hsp};
    hipError_t e = hipLaunchCooperativeKernel((void*)k_lstm, dim3(256), dim3(256),
                                              args, 0, stream);
    if (e != hipSuccess) {
      (void)hipGetLastError();  // clear; fall back (256 blocks @ 1/CU are co-resident)
      k_lstm<<<256, 256, 0, stream>>>(p2p, tkp, whp, hsp);
    }
  }

  k_fc<<<256, 64, 0, stream>>>(hseq, wfc, bfc, out);
}